// Round 4
// baseline (593.728 us; speedup 1.0000x reference)
//
#include <hip/hip_runtime.h>
#include <stdint.h>

#define NWIN 4096
#define NTOK 49
#define CDIM 192
#define NH   6
#define HD   32

typedef __attribute__((ext_vector_type(8))) short short8;
typedef __attribute__((ext_vector_type(4))) float floatx4;
typedef unsigned short ushort_t;
typedef unsigned int uint32;

// LDS row strides in bf16 elements: multiples of 8 (16-B alignment for b128),
// dword-stride mod 32 in {4,18} -> <=2-way bank aliasing (free per m136).
#define XS_S 200   // x rows [49][200]; later reused for attention output
#define QK_S 136   // per-pass q|k rows [49][136]: hh*64+{0..31}=q, +32..63=k
#define P_S  72    // probability rows [49][72] (cols 49..63 exact-0 K-pad)
#define VT_S 72    // V^T rows [64][72]: row = hh*32+d, col = token (>=49 -> 0)

// Manual layout (ushort offsets). Padded MFMA row-tiles (rows 49..63) do
// masked overrun READS that must stay inside the block's LDS:
//   xs overrun -> qks, qks overrun -> Pb, Pb overrun -> Vt; Vt never overruns.
#define OFF_XS   0              // 49*200 = 9800
#define OFF_QKS  9800           // 49*136 = 6664
#define OFF_PB   16464          // 49*72  = 3528
#define OFF_VT   19992          // 64*72  = 4608
#define LDS_TOT  24600          // 49200 B -> 3 blocks/CU (LDS limit)

__device__ __forceinline__ ushort_t f2bf(float f) {
    uint32 u = __float_as_uint(f);
    u += 0x7fffu + ((u >> 16) & 1u);   // round-to-nearest-even
    return (ushort_t)(u >> 16);
}

// Pre-convert weights to bf16 and pre-gather rpe bias into [6][49][64] fp32.
__global__ void wmsa_prologue(const float* __restrict__ qkv_w,
                              const float* __restrict__ proj_w,
                              const float* __restrict__ rpe_table,
                              const int*   __restrict__ rpe_idx,
                              ushort_t* __restrict__ qkv_wb,
                              ushort_t* __restrict__ proj_wb,
                              float* __restrict__ biasws)
{
    int i = blockIdx.x * 256 + threadIdx.x;
    if (i < 110592) {
        qkv_wb[i] = f2bf(qkv_w[i]);
    } else if (i < 147456) {
        proj_wb[i - 110592] = f2bf(proj_w[i - 110592]);
    } else if (i < 147456 + NH * NTOK * 64) {
        int r = i - 147456;
        int h = r / (NTOK * 64);
        int rem = r - h * (NTOK * 64);
        int n = rem >> 6, m = rem & 63;
        biasws[r] = (m < NTOK) ? rpe_table[rpe_idx[n * NTOK + m] * NH + h] : 0.f;
    }
}

// No afr/AGPR preload this version: round-3 counters showed arch 92 + accum 96
// (unified ~188) capped residency at 2 waves/SIMD. Target: <=170 unified so
// 3 blocks/CU (the LDS limit) actually materializes.
__global__ __launch_bounds__(256)
void wmsa_mfma(const float* __restrict__ x,
               const ushort_t* __restrict__ qkv_wb,
               const float* __restrict__ qkv_b,
               const ushort_t* __restrict__ proj_wb,
               const float* __restrict__ proj_b,
               const float* __restrict__ biasws,
               float* __restrict__ out)
{
    __shared__ alignas(16) ushort_t lds[LDS_TOT];
    ushort_t* const xs  = lds + OFF_XS;    // x (all passes), then attn output
    ushort_t* const qks = lds + OFF_QKS;   // per-pass q|k (2 heads)
    ushort_t* const Pb  = lds + OFF_PB;    // probabilities, wave-local rows
    ushort_t* const Vt  = lds + OFF_VT;    // per-pass V^T (2 heads), zero-pad

    const int b    = blockIdx.x;
    const int t    = threadIdx.x;
    const int w    = t >> 6;      // wave 0..3
    const int lane = t & 63;
    const int quad = lane >> 4;   // MFMA k-group
    const int c    = lane & 15;   // MFMA row/col within group
    const float scale = 0.17677669529663687f;   // 32^-0.5

    const float* xb = x + (size_t)b * (NTOK * CDIM);

    // ---------- stage x -> bf16 LDS (coalesced float4) ----------
    for (int i = t; i < (NTOK * CDIM) / 4; i += 256) {
        int e = i * 4;
        int n = e / CDIM, d = e - n * CDIM;
        float4 v = *(const float4*)(xb + e);
        ushort_t* p = &xs[n * XS_S + d];
        p[0] = f2bf(v.x); p[1] = f2bf(v.y); p[2] = f2bf(v.z); p[3] = f2bf(v.w);
    }
    __syncthreads();                                   // (A) x staged

    // attention output accumulators: 6 heads x 2 n-tiles x 4 rows = 48 VGPR,
    // all indices compile-time (unrolled loops) so no scratch spill.
    floatx4 out_acc[NH][2];
    const floatx4 zf = {0.f, 0.f, 0.f, 0.f};
    #pragma unroll
    for (int h = 0; h < NH; ++h) { out_acc[h][0] = zf; out_acc[h][1] = zf; }

    // wave w owns output-tile roles: hh_w = head-within-pass, half_w = 16-col half
    const int hh_w   = w >> 1;
    const int half_w = w & 1;
    const int jcol   = hh_w * 64 + half_w * 16 + c;    // q col base in qks

    #pragma unroll
    for (int pass = 0; pass < 3; ++pass) {
        // ----- qkv GEMM: wave computes its (q,k,v) 16-col tiles, 12 indep chains
        const int jbase = (2 * pass + hh_w) * HD + half_w * 16 + c;
        floatx4 acc[3][4];
        #pragma unroll
        for (int s = 0; s < 3; ++s)
            #pragma unroll
            for (int mt = 0; mt < 4; ++mt) acc[s][mt] = zf;

        #pragma unroll
        for (int ks = 0; ks < 6; ++ks) {
            short8 a4[4];
            #pragma unroll
            for (int mt = 0; mt < 4; ++mt)   // rows>=49 garbage, masked below
                a4[mt] = *(const short8*)&xs[(mt * 16 + c) * XS_S + ks * 32 + quad * 8];
            #pragma unroll
            for (int s = 0; s < 3; ++s) {
                short8 bf = *(const short8*)&qkv_wb[(s * CDIM + jbase) * CDIM + ks * 32 + quad * 8];
                #pragma unroll
                for (int mt = 0; mt < 4; ++mt)
                    acc[s][mt] = __builtin_amdgcn_mfma_f32_16x16x32_bf16(
                        a4[mt], bf, acc[s][mt], 0, 0, 0);
            }
        }
        // epilogue: q,k -> qks rows; v -> Vt transposed (row w*16+c, col token)
        float bq = qkv_b[jbase];
        float bk = qkv_b[CDIM + jbase];
        float bv = qkv_b[2 * CDIM + jbase];
        #pragma unroll
        for (int mt = 0; mt < 4; ++mt) {
            #pragma unroll
            for (int r = 0; r < 4; ++r) {
                int n = mt * 16 + quad * 4 + r;   // C: col=lane&15, row=quad*4+reg
                if (n < NTOK) {
                    qks[n * QK_S + jcol]      = f2bf((acc[0][mt][r] + bq) * scale);
                    qks[n * QK_S + jcol + 32] = f2bf(acc[1][mt][r] + bk);
                }
                Vt[(w * 16 + c) * VT_S + n] =
                    (n < NTOK) ? f2bf(acc[2][mt][r] + bv) : (ushort_t)0;
            }
        }
        __syncthreads();   // (B_p) qks + Vt ready

        // ----- attention, 2 heads, no intra-pass barriers (Pb wave-local) -----
        #pragma unroll
        for (int hh = 0; hh < 2; ++hh) {
            const int h = pass * 2 + hh;

            short8 aq = *(const short8*)&qks[(w * 16 + c) * QK_S + hh * 64 + quad * 8];
            floatx4 sacc[4];
            #pragma unroll
            for (int nt = 0; nt < 4; ++nt) {
                short8 bk8 = *(const short8*)&qks[(nt * 16 + c) * QK_S + hh * 64 + 32 + quad * 8];
                sacc[nt] = __builtin_amdgcn_mfma_f32_16x16x32_bf16(aq, bk8, zf, 0, 0, 0);
            }

            const float* bpb = biasws + h * (NTOK * 64);
            #pragma unroll
            for (int r = 0; r < 4; ++r) {
                int n  = w * 16 + quad * 4 + r;
                int nc = (n < NTOK) ? n : (NTOK - 1);   // clamp for pad rows
                float sv[4];
                #pragma unroll
                for (int nt = 0; nt < 4; ++nt) {
                    int col = nt * 16 + c;
                    float bias = bpb[nc * 64 + col];
                    sv[nt] = (col < NTOK) ? (sacc[nt][r] + bias) : -1e30f;
                }
                float m0 = fmaxf(fmaxf(sv[0], sv[1]), fmaxf(sv[2], sv[3]));
                m0 = fmaxf(m0, __shfl_xor(m0, 1));
                m0 = fmaxf(m0, __shfl_xor(m0, 2));
                m0 = fmaxf(m0, __shfl_xor(m0, 4));
                m0 = fmaxf(m0, __shfl_xor(m0, 8));
                float ex[4], s0 = 0.f;
                #pragma unroll
                for (int nt = 0; nt < 4; ++nt) { ex[nt] = __expf(sv[nt] - m0); s0 += ex[nt]; }
                s0 += __shfl_xor(s0, 1);
                s0 += __shfl_xor(s0, 2);
                s0 += __shfl_xor(s0, 4);
                s0 += __shfl_xor(s0, 8);
                float inv = 1.f / s0;
                if (n < NTOK) {
                    #pragma unroll
                    for (int nt = 0; nt < 4; ++nt)   // cols 49..63 exact 0 (K-pad)
                        Pb[n * P_S + nt * 16 + c] = f2bf(ex[nt] * inv);
                }
            }

            // PV accumulates straight into persistent registers.
            #pragma unroll
            for (int ks2 = 0; ks2 < 2; ++ks2) {
                short8 ap = *(const short8*)&Pb[(w * 16 + c) * P_S + ks2 * 32 + quad * 8];
                #pragma unroll
                for (int nt = 0; nt < 2; ++nt) {
                    short8 bv8 = *(const short8*)&Vt[(hh * HD + nt * 16 + c) * VT_S + ks2 * 32 + quad * 8];
                    out_acc[h][nt] = __builtin_amdgcn_mfma_f32_16x16x32_bf16(
                        ap, bv8, out_acc[h][nt], 0, 0, 0);
                }
            }
        }
        if (pass < 2) __syncthreads();   // (C_p) release qks/Pb/Vt for next pass
    }

    // ---------- attn-out registers -> xs (x dead after pass-2 GEMM) ----------
    #pragma unroll
    for (int h = 0; h < NH; ++h)
        #pragma unroll
        for (int nt = 0; nt < 2; ++nt)
            #pragma unroll
            for (int r = 0; r < 4; ++r) {
                int n = w * 16 + quad * 4 + r;
                if (n < NTOK)
                    xs[n * XS_S + h * HD + nt * 16 + c] = f2bf(out_acc[h][nt][r]);
            }
    __syncthreads();   // attn output visible to all waves

    // ---------- output projection: [49x192] @ [192x192]^T ----------
    floatx4 pacc[3][4];
    #pragma unroll
    for (int tt = 0; tt < 3; ++tt)
        #pragma unroll
        for (int mt = 0; mt < 4; ++mt) pacc[tt][mt] = zf;

    #pragma unroll
    for (int ks = 0; ks < 6; ++ks) {
        short8 a4[4];
        #pragma unroll
        for (int mt = 0; mt < 4; ++mt)
            a4[mt] = *(const short8*)&xs[(mt * 16 + c) * XS_S + ks * 32 + quad * 8];
        #pragma unroll
        for (int tt = 0; tt < 3; ++tt) {
            int j = (tt * 4 + w) * 16 + c;
            short8 bf = *(const short8*)&proj_wb[j * CDIM + ks * 32 + quad * 8];
            #pragma unroll
            for (int mt = 0; mt < 4; ++mt)
                pacc[tt][mt] = __builtin_amdgcn_mfma_f32_16x16x32_bf16(
                    a4[mt], bf, pacc[tt][mt], 0, 0, 0);
        }
    }
    #pragma unroll
    for (int tt = 0; tt < 3; ++tt) {
        int j = (tt * 4 + w) * 16 + c;
        float pb = proj_b[j];
        #pragma unroll
        for (int mt = 0; mt < 4; ++mt)
            #pragma unroll
            for (int r = 0; r < 4; ++r) {
                int n = mt * 16 + quad * 4 + r;
                if (n < NTOK)
                    out[((size_t)b * NTOK + n) * CDIM + j] = pacc[tt][mt][r] + pb;
            }
    }
}

extern "C" void kernel_launch(void* const* d_in, const int* in_sizes, int n_in,
                              void* d_out, int out_size, void* d_ws, size_t ws_size,
                              hipStream_t stream)
{
    const float* x      = (const float*)d_in[0];
    const float* qkv_w  = (const float*)d_in[1];
    const float* qkv_b  = (const float*)d_in[2];
    const float* proj_w = (const float*)d_in[3];
    const float* proj_b = (const float*)d_in[4];
    const float* rpe_t  = (const float*)d_in[5];
    const int*   rpe_i  = (const int*)d_in[6];
    float*       o      = (float*)d_out;

    // workspace layout: qkv_w bf16 (221184 B) | proj_w bf16 (73728 B) | bias fp32 (75264 B)
    ushort_t* qkv_wb  = (ushort_t*)d_ws;
    ushort_t* proj_wb = qkv_wb + 110592;
    float*    biasws  = (float*)((char*)d_ws + (110592 + 36864) * sizeof(ushort_t));

    int tot = 147456 + NH * NTOK * 64;
    wmsa_prologue<<<dim3((tot + 255) / 256), dim3(256), 0, stream>>>(
        qkv_w, proj_w, rpe_t, rpe_i, qkv_wb, proj_wb, biasws);
    wmsa_mfma<<<dim3(NWIN), dim3(256), 0, stream>>>(
        x, qkv_wb, qkv_b, proj_wb, proj_b, biasws, o);
}